// Round 5
// baseline (179.101 us; speedup 1.0000x reference)
//
#include <hip/hip_runtime.h>
#include <hip/hip_fp16.h>

// Problem constants
#define N_ 64
#define H_ 128
#define E_ 32
#define H1_ 128
#define H2_ 64
#define S_ 4096
// Wlin offsets: [users 0:32][items 32:64][langs 64:80][onehot 80:4176][tcf 4176:12368]
#define OFF_ITEMS 32
#define OFF_LANGS 64
#define OFF_ONEHOT 80
#define OFF_TCF 4176
#define OFF_TCF2 8272

typedef _Float16 half8 __attribute__((ext_vector_type(8)));
typedef short short8 __attribute__((ext_vector_type(8)));
typedef float floatx4 __attribute__((ext_vector_type(4)));

// ---------------------------------------------------------------------------
// Kernel 0: zero the sync/accum words (done[64] + accums[2] + counter).
__global__ void zero_sync(float* __restrict__ zr) {
    if (threadIdx.x < 68) zr[threadIdx.x] = 0.f;
}

// ---------------------------------------------------------------------------
// Kernel 1: fully fused. 640 blocks (10 lower-tri 32x32 tiles x 64 samples),
// 256 threads = 4 waves.
//
// Phases per block:
//  (a) stage W1^T (f16) into LDS union buffer wT; per-lane emb A-frags.
//  (b) build: wave w computes a 16-row tile of aL (w=0,1) or bL (w=2,3)
//      via 8x mfma_f32_16x16x32_f16; B-frags = 1 ds_read_b128 from W1^T.
//  (c) restage wT as W2^T (f16); hoist W2 A-operand frags (16 ds_read_b128),
//      b2/Ws as float4, per-wave b-row frags (wave-constant hf = wv&1).
//  (d) main: per 16-pair group (all sharing i=li): h1 = relu(a_i + b_j) f16;
//      acc[nt] = mfma(W2T_frag, h1, acc)  -> D col = pair, row = h2-col.
//      Epilogue per lane: dot(Ws) partial -> 2 shfl -> tanh -> 8 shfl pair-sum
//      -> LDS sT/sC.
//  (e) segP slab write + threadfence + per-n ticket; 10th finisher of n runs
//      finalize(n) in-kernel (agent-scope atomic loads of segP per G16);
//      64th finalizer computes the loss.
__global__ __launch_bounds__(256) void fused(
    const int* __restrict__ skills, const float* __restrict__ emb_table,
    const float* __restrict__ W1, const float* __restrict__ b1,
    const float* __restrict__ W2, const float* __restrict__ targets,
    const float* __restrict__ users, const float* __restrict__ items,
    const float* __restrict__ langs, const void* __restrict__ mask,
    const float* __restrict__ b2, const float* __restrict__ Ws,
    const float* __restrict__ bs, const float* __restrict__ Wlin,
    const float* __restrict__ blin,
    float* __restrict__ segP, int* __restrict__ done,
    float* __restrict__ accums, int* __restrict__ counter,
    float* __restrict__ out) {

    int bid = blockIdx.x;
    int tid = threadIdx.x;
    int n = bid / 10;
    int t = bid % 10;
    int ti = 0;
    while ((ti + 1) * (ti + 2) / 2 <= t) ti++;
    int tj = t - ti * (ti + 1) / 2;
    int i0 = ti * 32, j0 = tj * 32;
    bool diag = (ti == tj);

    __shared__ __align__(16) _Float16 aL[32][136];
    __shared__ __align__(16) _Float16 bL[32][136];
    __shared__ __align__(16) _Float16 wT[9216];   // W1^T [128][72] then W2^T [64][136]
    __shared__ float tgt[32], sT[32], sC[32];
    __shared__ int tick_s;
    __shared__ float cred[4], s1[4], s2[4];

    int lane = tid & 63, wv = tid >> 6;
    int hi = lane >> 4, lo = lane & 15;

    // ---- (a) stage W1^T: wT[c*72 + r] = W1[r][c], r<64 (e-dim), c<128 (k-dim)
    for (int idx = tid; idx < 2048; idx += 256) {
        int r = idx >> 5;
        int c4 = (idx & 31) * 4;
        float4 v = *(const float4*)(W1 + r * 128 + c4);
        wT[(c4 + 0) * 72 + r] = (_Float16)v.x;
        wT[(c4 + 1) * 72 + r] = (_Float16)v.y;
        wT[(c4 + 2) * 72 + r] = (_Float16)v.z;
        wT[(c4 + 3) * 72 + r] = (_Float16)v.w;
    }

    bool isA = (wv < 2);
    int rbase = (isA ? i0 : j0) + (wv & 1) * 16;
    int woff = isA ? 0 : 32;
    int sk = skills[n * H_ + rbase + lo];
    float4 e0 = *(const float4*)(emb_table + (size_t)sk * 32 + 8 * hi);
    float4 e1 = *(const float4*)(emb_table + (size_t)sk * 32 + 8 * hi + 4);
    half8 afrag;
    afrag[0] = (_Float16)e0.x; afrag[1] = (_Float16)e0.y;
    afrag[2] = (_Float16)e0.z; afrag[3] = (_Float16)e0.w;
    afrag[4] = (_Float16)e1.x; afrag[5] = (_Float16)e1.y;
    afrag[6] = (_Float16)e1.z; afrag[7] = (_Float16)e1.w;

    if (tid < 32) {
        tgt[tid] = targets[n * H_ + j0 + tid];
        sT[tid] = 0.f;
        sC[tid] = 0.f;
    }
    __syncthreads();

    // ---- (b) build phase
    {
        _Float16 (*dst)[136] = isA ? aL : bL;
        int rloc0 = (wv & 1) * 16 + 4 * hi;
        #pragma unroll
        for (int ct = 0; ct < 8; ct++) {
            float cinit = isA ? b1[16 * ct + lo] : 0.f;
            floatx4 accB = (floatx4){cinit, cinit, cinit, cinit};
            half8 bf = *(const half8*)(&wT[(16 * ct + lo) * 72 + woff + 8 * hi]);
            accB = __builtin_amdgcn_mfma_f32_16x16x32_f16(afrag, bf, accB, 0, 0, 0);
            #pragma unroll
            for (int q = 0; q < 4; q++)
                dst[rloc0 + q][16 * ct + lo] = (_Float16)accB[q];
        }
    }
    __syncthreads();   // aL/bL ready; W1^T dead

    // ---- (c) stage W2^T: wT[c*136 + r] = W2[r][c], r<128 (k), c<64 (col)
    for (int idx = tid; idx < 2048; idx += 256) {
        int r = idx >> 4;
        int c4 = (idx & 15) * 4;
        float4 v = *(const float4*)(W2 + r * 64 + c4);
        wT[(c4 + 0) * 136 + r] = (_Float16)v.x;
        wT[(c4 + 1) * 136 + r] = (_Float16)v.y;
        wT[(c4 + 2) * 136 + r] = (_Float16)v.z;
        wT[(c4 + 3) * 136 + r] = (_Float16)v.w;
    }
    __syncthreads();

    // W2^T A-operand fragments (identical values to the old B-frags)
    half8 wfragT[4][4];
    #pragma unroll
    for (int kk = 0; kk < 4; kk++)
        #pragma unroll
        for (int nt = 0; nt < 4; nt++)
            wfragT[kk][nt] = *(const half8*)(&wT[(16 * nt + lo) * 136 + 32 * kk + 8 * hi]);

    floatx4 b2v[4], wsv[4];
    #pragma unroll
    for (int nt = 0; nt < 4; nt++) {
        b2v[nt] = *(const floatx4*)(b2 + 16 * nt + 4 * hi);
        wsv[nt] = *(const floatx4*)(Ws + 16 * nt + 4 * hi);
    }
    float bsv = bs[0];

    // hoist per-wave b-row fragments: hf = g&1 = wv&1 is wave-constant
    int hf = wv & 1;
    int lj = 16 * hf + lo;                 // this lane's pair j-offset
    half8 bfx[4];
    {
        const _Float16* brow = &bL[lj][0];
        #pragma unroll
        for (int kk = 0; kk < 4; kk++)
            bfx[kk] = *(const half8*)(brow + 32 * kk + 8 * hi);
    }
    float tgtv = tgt[lj];

    // ---- (d) main loop
    for (int g = wv; g < 64; g += 4) {
        int li = g >> 1;
        if (diag && li <= 16 * hf) continue;

        const _Float16* arow = &aL[li][0];
        floatx4 acc[4];
        #pragma unroll
        for (int nt = 0; nt < 4; nt++) acc[nt] = (floatx4){0.f, 0.f, 0.f, 0.f};

        #pragma unroll
        for (int kk = 0; kk < 4; kk++) {
            half8 av = *(const half8*)(arow + 32 * kk + 8 * hi);  // broadcast
            half8 s = av + bfx[kk];                  // v_pk_add_f16
            short8 bits = __builtin_bit_cast(short8, s);
            short8 sgn = bits >> 15;
            bits &= ~sgn;                            // relu via sign trick
            half8 h = __builtin_bit_cast(half8, bits);
            acc[0] = __builtin_amdgcn_mfma_f32_16x16x32_f16(wfragT[kk][0], h, acc[0], 0, 0, 0);
            acc[1] = __builtin_amdgcn_mfma_f32_16x16x32_f16(wfragT[kk][1], h, acc[1], 0, 0, 0);
            acc[2] = __builtin_amdgcn_mfma_f32_16x16x32_f16(wfragT[kk][2], h, acc[2], 0, 0, 0);
            acc[3] = __builtin_amdgcn_mfma_f32_16x16x32_f16(wfragT[kk][3], h, acc[3], 0, 0, 0);
        }

        // epilogue: D row = h2-col (16nt+4hi+q), col = pair (lo)
        float part = 0.f;
        #pragma unroll
        for (int nt = 0; nt < 4; nt++)
            #pragma unroll
            for (int q = 0; q < 4; q++)
                part += fmaxf(acc[nt][q] + b2v[nt][q], 0.f) * wsv[nt][q];
        part += __shfl_xor(part, 16, 64);
        part += __shfl_xor(part, 32, 64);            // full 64-col dot, all replicas

        float x = part + bsv;
        float e2 = __expf(2.f * x);
        float sv = 1.f - 2.f * __builtin_amdgcn_rcpf(e2 + 1.f);   // tanh
        bool valid = (!diag) || (li > lj);
        sv = valid ? sv : 0.f;
        float svT = sv, svC = sv * tgtv;
        #pragma unroll
        for (int m = 1; m <= 8; m <<= 1) {
            svT += __shfl_xor(svT, m, 64);
            svC += __shfl_xor(svC, m, 64);
        }
        if (lane == 0) {
            atomicAdd(&sT[li], svT);                 // ds_add_f32
            atomicAdd(&sC[li], svC);
        }
    }

    __syncthreads();
    // ---- (e) slab write + ticket
    if (tid < 32) {
        segP[(size_t)bid * 64 + tid]      = sT[tid];
        segP[(size_t)bid * 64 + 32 + tid] = sC[tid];
    }
    __threadfence();                                 // release slab to device
    __syncthreads();
    if (tid == 0) tick_s = atomicAdd(&done[n], 1);
    __syncthreads();
    if (tick_s != 9) return;                         // only the 10th finisher of n
    __threadfence();

    // ================= finalize(n) — 256 threads, rows h<128 active ========
    int h = tid;
    bool act = h < 128;
    int nh = n * H_ + (act ? h : 0);
    int sk2 = skills[nh];

    // mask dtype sniff: bool(1B) vs int32(4B); 16 words safe either way
    const unsigned* mw = (const unsigned*)mask;
    bool byte_layout = false;
    #pragma unroll
    for (int q = 0; q < 16; q++) byte_layout |= (mw[q] > 1u);
    float m = byte_layout ? (((const unsigned char*)mask)[nh] ? 1.f : 0.f)
                          : (mw[nh] ? 1.f : 0.f);

    float tterm = 0.f, sTt = 0.f, sCt = 0.f;
    if (act) {
        int ti2 = h >> 5, r = h & 31;
        int tb = ti2 * (ti2 + 1) / 2;
        for (int tj2 = 0; tj2 <= ti2; tj2++) {
            const float* p = segP + (size_t)(n * 10 + tb + tj2) * 64;
            // agent-scope loads: slabs may live in another XCD's L2 (G16)
            sTt += __hip_atomic_load(p + r, __ATOMIC_RELAXED, __HIP_MEMORY_SCOPE_AGENT);
            sCt += __hip_atomic_load(p + 32 + r, __ATOMIC_RELAXED, __HIP_MEMORY_SCOPE_AGENT);
        }
        tterm = sTt * Wlin[OFF_TCF + sk2] + sCt * Wlin[OFF_TCF2 + sk2];
        if (h < 32) tterm += users[n * 32 + h] * Wlin[h];
    }
    {
        float v = tterm;
        #pragma unroll
        for (int mm = 1; mm <= 32; mm <<= 1) v += __shfl_xor(v, mm, 64);
        if (lane == 0) cred[wv] = v;
    }
    __syncthreads();
    float c = cred[0] + cred[1] + cred[2] + cred[3] + blin[0];

    float z = 0.f, bce = 0.f;
    if (act) {
        z = c + Wlin[OFF_ONEHOT + sk2];
        const float4* ip = (const float4*)(items + (size_t)nh * 32);
        #pragma unroll
        for (int i4 = 0; i4 < 8; i4++) {
            float4 v = ip[i4];
            z += v.x * Wlin[OFF_ITEMS + 4 * i4]     + v.y * Wlin[OFF_ITEMS + 4 * i4 + 1]
               + v.z * Wlin[OFF_ITEMS + 4 * i4 + 2] + v.w * Wlin[OFF_ITEMS + 4 * i4 + 3];
        }
        const float4* lp = (const float4*)(langs + (size_t)nh * 16);
        #pragma unroll
        for (int l4 = 0; l4 < 4; l4++) {
            float4 v = lp[l4];
            z += v.x * Wlin[OFF_LANGS + 4 * l4]     + v.y * Wlin[OFF_LANGS + 4 * l4 + 1]
               + v.z * Wlin[OFF_LANGS + 4 * l4 + 2] + v.w * Wlin[OFF_LANGS + 4 * l4 + 3];
        }
        out[1 + nh] = 1.f / (1.f + __expf(-z));
        float y = targets[nh];
        bce = fmaxf(z, 0.f) - z * y + log1pf(__expf(-fabsf(z)));
    }

    {
        float x1 = act ? bce * m : 0.f;
        float x2 = act ? m : 0.f;
        #pragma unroll
        for (int mm = 1; mm <= 32; mm <<= 1) {
            x1 += __shfl_xor(x1, mm, 64);
            x2 += __shfl_xor(x2, mm, 64);
        }
        if (lane == 0) { s1[wv] = x1; s2[wv] = x2; }
    }
    __syncthreads();
    if (tid == 0) {
        atomicAdd(&accums[0], s1[0] + s1[1] + s1[2] + s1[3]);
        atomicAdd(&accums[1], s2[0] + s2[1] + s2[2] + s2[3]);
        __threadfence();
        if (atomicAdd(counter, 1) == N_ - 1) {       // last finalizer overall
            float a = atomicAdd(&accums[0], 0.f);    // device-coherent reads
            float b = atomicAdd(&accums[1], 0.f);
            out[0] = a / fmaxf(b, 1.f);
        }
    }
}

// ---------------------------------------------------------------------------
extern "C" void kernel_launch(void* const* d_in, const int* in_sizes, int n_in,
                              void* d_out, int out_size, void* d_ws, size_t ws_size,
                              hipStream_t stream) {
    const int*   skills  = (const int*)d_in[0];
    const float* targets = (const float*)d_in[1];
    const float* users   = (const float*)d_in[2];
    const float* items   = (const float*)d_in[3];
    const float* langs   = (const float*)d_in[4];
    const void*  mask    = (const void*)d_in[5];
    const float* emb     = (const float*)d_in[6];
    const float* W1      = (const float*)d_in[7];
    const float* b1      = (const float*)d_in[8];
    const float* W2      = (const float*)d_in[9];
    const float* b2      = (const float*)d_in[10];
    const float* Ws      = (const float*)d_in[11];
    const float* bs      = (const float*)d_in[12];
    const float* Wlin    = (const float*)d_in[13];
    const float* blin    = (const float*)d_in[14];

    char* ws = (char*)d_ws;
    float* segP    = (float*)ws;                    // 640*64 f32 = 160 KB
    float* syncw   = (float*)(ws + (192u << 10));   // done[64] + accums[2] + counter
    int*   done    = (int*)syncw;
    float* accums  = syncw + 64;
    int*   counter = (int*)(syncw + 66);

    zero_sync<<<1, 128, 0, stream>>>(syncw);
    fused<<<N_ * 10, 256, 0, stream>>>(skills, emb, W1, b1, W2, targets,
                                       users, items, langs, mask,
                                       b2, Ws, bs, Wlin, blin,
                                       segP, done, accums, counter, (float*)d_out);
}

// Round 6
// 114.297 us; speedup vs baseline: 1.5670x; 1.5670x over previous
//
#include <hip/hip_runtime.h>
#include <hip/hip_fp16.h>

// Problem constants
#define N_ 64
#define H_ 128
#define E_ 32
#define H1_ 128
#define H2_ 64
#define S_ 4096
// Wlin offsets: [users 0:32][items 32:64][langs 64:80][onehot 80:4176][tcf 4176:12368]
#define OFF_ITEMS 32
#define OFF_LANGS 64
#define OFF_ONEHOT 80
#define OFF_TCF 4176
#define OFF_TCF2 8272

typedef _Float16 half8 __attribute__((ext_vector_type(8)));
typedef short short8 __attribute__((ext_vector_type(8)));
typedef float floatx4 __attribute__((ext_vector_type(4)));

// ---------------------------------------------------------------------------
// Kernel 1: fused build + pairwise MLP over the lower triangle.
// Block = 32x32 (i,j) tile of one sample n. 256 threads = 4 waves.
//
// Build: wave w computes a 16-row tile of aL (w=0,1: b1 + emb_i@W1[0:32]) or
// bL (w=2,3: emb_j@W1[32:64]) via 8x mfma_f32_16x16x32_f16 (K=32=E).
// Main: per 16-pair group (shared i=li): h1 = relu(a_i + b_j) f16;
//   acc[nt] = mfma(W2T_frag, h1, acc)  -> D col = pair (lo), row = h2-col.
//   Epilogue per lane: partial dot(Ws) -> 2 shfl -> 1 tanh -> 8 shfl -> LDS.
// Output: private segP slab per block (no global atomics, no zero-init).
// NOTE: no __threadfence() anywhere — cross-block visibility comes from the
// kernel boundary (r5 post-mortem: per-block device fences cost ~90 us).
__global__ __launch_bounds__(256) void pair_mlp(
    const int* __restrict__ skills, const float* __restrict__ emb_table,
    const float* __restrict__ W1, const float* __restrict__ b1,
    const float* __restrict__ W2, const float* __restrict__ targets,
    const float* __restrict__ b2, const float* __restrict__ Ws,
    const float* __restrict__ bs,
    float* __restrict__ segP, float* __restrict__ accums_region) {

    int bid = blockIdx.x;
    int tid = threadIdx.x;

    // zero accums[2] + counter + pad (visible to finalize via kernel boundary)
    if (bid == 0 && tid < 4) accums_region[tid] = 0.f;

    int n = bid / 10;
    int t = bid % 10;
    int ti = 0;
    while ((ti + 1) * (ti + 2) / 2 <= t) ti++;
    int tj = t - ti * (ti + 1) / 2;
    int i0 = ti * 32, j0 = tj * 32;
    bool diag = (ti == tj);

    __shared__ __align__(16) _Float16 aL[32][136];  // +8 pad: 2-way banks (free)
    __shared__ __align__(16) _Float16 bL[32][136];
    __shared__ float tgt[32];
    __shared__ float sT[32], sC[32];

    int lane = tid & 63, wv = tid >> 6;
    int hi = lane >> 4, lo = lane & 15;

    // ---------------- build phase ----------------
    bool isA = (wv < 2);
    int rbase = (isA ? i0 : j0) + (wv & 1) * 16;    // first of this wave's 16 rows
    int woff = isA ? 0 : 32;                        // W1 half (top for a, bottom for b)

    int sk = skills[n * H_ + rbase + lo];
    float4 e0 = *(const float4*)(emb_table + (size_t)sk * 32 + 8 * hi);
    float4 e1 = *(const float4*)(emb_table + (size_t)sk * 32 + 8 * hi + 4);
    half8 afrag;
    afrag[0] = (_Float16)e0.x; afrag[1] = (_Float16)e0.y;
    afrag[2] = (_Float16)e0.z; afrag[3] = (_Float16)e0.w;
    afrag[4] = (_Float16)e1.x; afrag[5] = (_Float16)e1.y;
    afrag[6] = (_Float16)e1.z; afrag[7] = (_Float16)e1.w;

    {
        _Float16 (*dst)[136] = isA ? aL : bL;
        int rloc0 = (wv & 1) * 16 + 4 * hi;
        #pragma unroll
        for (int ct = 0; ct < 8; ct++) {
            float cinit = isA ? b1[16 * ct + lo] : 0.f;
            floatx4 accB = (floatx4){cinit, cinit, cinit, cinit};
            half8 bf;
            #pragma unroll
            for (int e = 0; e < 8; e++)
                bf[e] = (_Float16)W1[(woff + 8 * hi + e) * 128 + 16 * ct + lo];
            accB = __builtin_amdgcn_mfma_f32_16x16x32_f16(afrag, bf, accB, 0, 0, 0);
            #pragma unroll
            for (int q = 0; q < 4; q++)
                dst[rloc0 + q][16 * ct + lo] = (_Float16)accB[q];
        }
    }

    if (tid < 32) {
        tgt[tid] = targets[n * H_ + j0 + tid];
        sT[tid] = 0.f;
        sC[tid] = 0.f;
    }

    // W2^T A-operand fragments straight from global f32 (L2-hot).
    // wfragT[kk][nt][e] = W2[(32kk+8hi+e)][16nt+lo] — same values as the
    // round-4 B-frags; as the A operand, D's column becomes the pair index.
    half8 wfragT[4][4];
    #pragma unroll
    for (int kk = 0; kk < 4; kk++)
        #pragma unroll
        for (int nt = 0; nt < 4; nt++) {
            half8 wf;
            #pragma unroll
            for (int e = 0; e < 8; e++)
                wf[e] = (_Float16)W2[(32 * kk + 8 * hi + e) * 64 + 16 * nt + lo];
            wfragT[kk][nt] = wf;
        }

    floatx4 b2v[4], wsv[4];
    #pragma unroll
    for (int nt = 0; nt < 4; nt++) {
        b2v[nt] = *(const floatx4*)(b2 + 16 * nt + 4 * hi);
        wsv[nt] = *(const floatx4*)(Ws + 16 * nt + 4 * hi);
    }
    float bsv = bs[0];

    __syncthreads();

    // hoist per-wave b-row fragments: hf = g&1 = wv&1 is wave-constant
    int hf = wv & 1;
    int lj = 16 * hf + lo;                 // this lane's pair j-offset
    half8 bfx[4];
    {
        const _Float16* brow = &bL[lj][0];
        #pragma unroll
        for (int kk = 0; kk < 4; kk++)
            bfx[kk] = *(const half8*)(brow + 32 * kk + 8 * hi);
    }
    float tgtv = tgt[lj];

    // ---------------- main phase ----------------
    for (int g = wv; g < 64; g += 4) {
        int li = g >> 1;        // i - i0 (shared by the group's 16 pairs)
        if (diag && li <= 16 * hf) continue;   // no valid pairs in group

        const _Float16* arow = &aL[li][0];
        floatx4 acc[4];
        #pragma unroll
        for (int nt = 0; nt < 4; nt++) acc[nt] = (floatx4){0.f, 0.f, 0.f, 0.f};

        #pragma unroll
        for (int kk = 0; kk < 4; kk++) {
            half8 av = *(const half8*)(arow + 32 * kk + 8 * hi);  // broadcast
            half8 s = av + bfx[kk];                  // v_pk_add_f16
            short8 bits = __builtin_bit_cast(short8, s);
            short8 sgn = bits >> 15;
            bits &= ~sgn;                            // relu via sign trick
            half8 h = __builtin_bit_cast(half8, bits);
            acc[0] = __builtin_amdgcn_mfma_f32_16x16x32_f16(wfragT[kk][0], h, acc[0], 0, 0, 0);
            acc[1] = __builtin_amdgcn_mfma_f32_16x16x32_f16(wfragT[kk][1], h, acc[1], 0, 0, 0);
            acc[2] = __builtin_amdgcn_mfma_f32_16x16x32_f16(wfragT[kk][2], h, acc[2], 0, 0, 0);
            acc[3] = __builtin_amdgcn_mfma_f32_16x16x32_f16(wfragT[kk][3], h, acc[3], 0, 0, 0);
        }

        // epilogue: D row = h2-col (16nt+4hi+q), col = pair (lo)
        float part = 0.f;
        #pragma unroll
        for (int nt = 0; nt < 4; nt++)
            #pragma unroll
            for (int q = 0; q < 4; q++)
                part += fmaxf(acc[nt][q] + b2v[nt][q], 0.f) * wsv[nt][q];
        part += __shfl_xor(part, 16, 64);
        part += __shfl_xor(part, 32, 64);            // full 64-col dot, replicated

        float x = part + bsv;
        float e2 = __expf(2.f * x);
        float sv = 1.f - 2.f * __builtin_amdgcn_rcpf(e2 + 1.f);   // tanh
        bool valid = (!diag) || (li > lj);
        sv = valid ? sv : 0.f;
        float svT = sv, svC = sv * tgtv;
        #pragma unroll
        for (int m = 1; m <= 8; m <<= 1) {           // sum the 16 pairs (lo dim)
            svT += __shfl_xor(svT, m, 64);
            svC += __shfl_xor(svC, m, 64);
        }
        if (lane == 0) {
            atomicAdd(&sT[li], svT);                 // ds_add_f32
            atomicAdd(&sC[li], svC);
        }
    }

    __syncthreads();
    // private partial slab: no global atomics, no zero-init dependency
    if (tid < 32) {
        segP[(size_t)bid * 64 + tid]      = sT[tid];
        segP[(size_t)bid * 64 + 32 + tid] = sC[tid];
    }
}

// ---------------------------------------------------------------------------
// Kernel 2: per-(n,h) final linear + sigmoid + masked BCE; last block divides.
// grid 64 x 128 (one block per n, 2 waves)
__global__ void finalize(const int* __restrict__ skills,
                         const float* __restrict__ targets,
                         const float* __restrict__ users,
                         const float* __restrict__ items,
                         const float* __restrict__ langs,
                         const void* __restrict__ mask,
                         const float* __restrict__ Wlin,
                         const float* __restrict__ blin,
                         const float* __restrict__ segP,
                         float* __restrict__ out,
                         float* __restrict__ accums,
                         int* __restrict__ counter) {
    int n = blockIdx.x, h = threadIdx.x;
    int nh = n * H_ + h;
    int sk = skills[nh];

    // mask dtype sniff: bool(1B) vs int32(4B). 16 words, in-bounds either way.
    const unsigned* mw = (const unsigned*)mask;
    bool byte_layout = false;
    #pragma unroll
    for (int q = 0; q < 16; q++) byte_layout |= (mw[q] > 1u);
    float m = byte_layout ? (((const unsigned char*)mask)[nh] ? 1.f : 0.f)
                          : (mw[nh] ? 1.f : 0.f);

    // gather this row's seg partials from the <=4 contributing tiles
    int ti = h >> 5, r = h & 31;
    int tb = ti * (ti + 1) / 2;
    float sT = 0.f, sC = 0.f;
    for (int tj = 0; tj <= ti; tj++) {
        const float* p = segP + (size_t)(n * 10 + tb + tj) * 64;
        sT += p[r];
        sC += p[32 + r];
    }

    // per-n constant part: users.Wlin[0:32] + tcf-dot (+blin)
    float tterm = sT * Wlin[OFF_TCF + sk] + sC * Wlin[OFF_TCF2 + sk];
    if (h < 32) tterm += users[n * 32 + h] * Wlin[h];

    __shared__ float cred[2];
    {
        float v = tterm;
        #pragma unroll
        for (int mm = 1; mm <= 32; mm <<= 1) v += __shfl_xor(v, mm, 64);
        if ((h & 63) == 0) cred[h >> 6] = v;
    }
    __syncthreads();
    float c = cred[0] + cred[1] + blin[0];

    float z = c + Wlin[OFF_ONEHOT + sk];
    const float4* ip = (const float4*)(items + (size_t)nh * 32);
    #pragma unroll
    for (int i4 = 0; i4 < 8; i4++) {
        float4 v = ip[i4];
        z += v.x * Wlin[OFF_ITEMS + 4 * i4]     + v.y * Wlin[OFF_ITEMS + 4 * i4 + 1]
           + v.z * Wlin[OFF_ITEMS + 4 * i4 + 2] + v.w * Wlin[OFF_ITEMS + 4 * i4 + 3];
    }
    const float4* lp = (const float4*)(langs + (size_t)nh * 16);
    #pragma unroll
    for (int l4 = 0; l4 < 4; l4++) {
        float4 v = lp[l4];
        z += v.x * Wlin[OFF_LANGS + 4 * l4]     + v.y * Wlin[OFF_LANGS + 4 * l4 + 1]
           + v.z * Wlin[OFF_LANGS + 4 * l4 + 2] + v.w * Wlin[OFF_LANGS + 4 * l4 + 3];
    }

    out[1 + nh] = 1.f / (1.f + __expf(-z));

    float y = targets[nh];
    float bce = fmaxf(z, 0.f) - z * y + log1pf(__expf(-fabsf(z)));

    __shared__ float s1[2], s2[2];
    {
        float x1 = bce * m, x2 = m;
        #pragma unroll
        for (int mm = 1; mm <= 32; mm <<= 1) {
            x1 += __shfl_xor(x1, mm, 64);
            x2 += __shfl_xor(x2, mm, 64);
        }
        if ((h & 63) == 0) { s1[h >> 6] = x1; s2[h >> 6] = x2; }
    }
    __syncthreads();
    if (h == 0) {
        atomicAdd(&accums[0], s1[0] + s1[1]);
        atomicAdd(&accums[1], s2[0] + s2[1]);
        __threadfence();
        if (atomicAdd(counter, 1) == N_ - 1) {       // last block overall
            float a = atomicAdd(&accums[0], 0.f);    // device-coherent read
            float b = atomicAdd(&accums[1], 0.f);
            out[0] = a / fmaxf(b, 1.f);
        }
    }
}

// ---------------------------------------------------------------------------
extern "C" void kernel_launch(void* const* d_in, const int* in_sizes, int n_in,
                              void* d_out, int out_size, void* d_ws, size_t ws_size,
                              hipStream_t stream) {
    const int*   skills  = (const int*)d_in[0];
    const float* targets = (const float*)d_in[1];
    const float* users   = (const float*)d_in[2];
    const float* items   = (const float*)d_in[3];
    const float* langs   = (const float*)d_in[4];
    const void*  mask    = (const void*)d_in[5];
    const float* emb     = (const float*)d_in[6];
    const float* W1      = (const float*)d_in[7];
    const float* b1      = (const float*)d_in[8];
    const float* W2      = (const float*)d_in[9];
    const float* b2      = (const float*)d_in[10];
    const float* Ws      = (const float*)d_in[11];
    const float* bs      = (const float*)d_in[12];
    const float* Wlin    = (const float*)d_in[13];
    const float* blin    = (const float*)d_in[14];

    char* ws = (char*)d_ws;
    float* segP    = (float*)ws;                    // 640*64 f32 = 160 KB
    float* accums  = (float*)(ws + (256u << 10));   // accums[2] + counter + pad
    int*   counter = (int*)(accums + 2);

    pair_mlp<<<N_ * 10, 256, 0, stream>>>(skills, emb, W1, b1, W2, targets,
                                          b2, Ws, bs, segP, accums);
    finalize<<<N_, H_, 0, stream>>>(skills, targets, users, items, langs, mask,
                                    Wlin, blin, segP, (float*)d_out, accums, counter);
}